// Round 4
// baseline (2124.226 us; speedup 1.0000x reference)
//
#include <hip/hip_runtime.h>
#include <math.h>

#define B_   32
#define H_   16
#define KV_  2048
#define D_   128
#define E_   2048
#define NQKV 6144

// ---------------------------------------------------------------------------
// Thin-M GEMM: C(32xN) = A(32xK) @ W(KxN) + bias, fp32, full-K per block.
// Block handles TN output columns; 256 threads; LDS-staged tiles.
// Xs padded [32][65] so row-broadcast reads spread across banks.
// ---------------------------------------------------------------------------
template <int TN>
__global__ __launch_bounds__(256) void gemm32(const float* __restrict__ A,
                                              const float* __restrict__ W,
                                              const float* __restrict__ bias,
                                              float* __restrict__ C,
                                              int K, int N) {
  __shared__ float Xs[32][65];
  __shared__ float Ws[64][TN];
  const int tid  = threadIdx.x;
  const int n0   = blockIdx.x * TN;
  const int col  = tid % TN;
  const int rowg = tid / TN;          // 0..(256/TN - 1)
  constexpr int NG  = 256 / TN;       // row groups
  constexpr int RPT = 32 / NG;        // rows per thread

  float acc[RPT];
#pragma unroll
  for (int r = 0; r < RPT; ++r) acc[r] = 0.f;

  for (int k0 = 0; k0 < K; k0 += 64) {
    for (int idx = tid; idx < 32 * 64; idx += 256) {
      int m = idx >> 6, kk = idx & 63;
      Xs[m][kk] = A[(size_t)m * K + k0 + kk];
    }
    for (int idx = tid; idx < 64 * TN; idx += 256) {
      int kk = idx / TN, nn = idx % TN;
      Ws[kk][nn] = W[(size_t)(k0 + kk) * N + n0 + nn];
    }
    __syncthreads();
#pragma unroll
    for (int kk = 0; kk < 64; ++kk) {
      float wv = Ws[kk][col];
#pragma unroll
      for (int r = 0; r < RPT; ++r)
        acc[r] = fmaf(Xs[rowg + NG * r][kk], wv, acc[r]);
    }
    __syncthreads();
  }
  float bv = bias[n0 + col];
#pragma unroll
  for (int r = 0; r < RPT; ++r)
    C[(size_t)(rowg + NG * r) * N + n0 + col] = acc[r] + bv;
}

// ---------------------------------------------------------------------------
// Fused: KV-cache copy + scores + softmax + PV + mask_new write.
// One block per (b,h); 256 threads = 4 waves; each wave streams 8 contiguous
// rows per macro-iter (4 float4 loads in flight/lane). q pre-scaled in regs.
// ---------------------------------------------------------------------------
__global__ __launch_bounds__(256) void attn_fused(
    const float* __restrict__ kcache, const float* __restrict__ vcache,
    const float* __restrict__ mask,   const float* __restrict__ qkv,
    float* __restrict__ Kc, float* __restrict__ Vc, float* __restrict__ ctx,
    float* __restrict__ mask_new) {
  __shared__ float sc[KV_ + 1];
  __shared__ float red[4];
  __shared__ float ctx_s[4][D_];

  const int bh   = blockIdx.x;
  const int b    = bh >> 4;
  const int h    = bh & 15;
  const int tid  = threadIdx.x;
  const int w    = tid >> 6;         // wave 0..3
  const int lane = tid & 63;
  const int half = lane >> 5;
  const int c    = (lane & 31) * 4;  // column group

  const float inv_sqrt_d = 0.08838834764831845f;  // 1/sqrt(128)

  const float* kc_in  = kcache + (size_t)bh * KV_ * D_;
  const float* vc_in  = vcache + (size_t)bh * KV_ * D_;
  float*       kc_out = Kc + (size_t)bh * (KV_ + 1) * D_;
  float*       vc_out = Vc + (size_t)bh * (KV_ + 1) * D_;
  const float* qp  = qkv + (size_t)b * NQKV + h * D_;
  const float* knp = qp + E_;
  const float* vnp = qp + 2 * E_;
  const float* mrow = mask + (size_t)b * KV_;

  float4 qr = *(const float4*)(qp + c);
  qr.x *= inv_sqrt_d; qr.y *= inv_sqrt_d; qr.z *= inv_sqrt_d; qr.w *= inv_sqrt_d;

  // ---- mask_new (one head per batch does it; mask row is L2-hot) ----
  if (h == 0) {
    float* mout = mask_new + (size_t)b * (KV_ + 1);
    for (int k = tid; k < KV_; k += 256) mout[k] = mrow[k];
    if (tid == 0) mout[KV_] = 1.f;
  }

  // ---- Pass 1: copy K rows + compute raw scores ----
  for (int r0 = 0; r0 < KV_; r0 += 32) {
    float4 kv[4];
#pragma unroll
    for (int u = 0; u < 4; ++u) {
      int row = r0 + 8 * w + 2 * u + half;
      kv[u] = *(const float4*)(kc_in + (size_t)row * D_ + c);
    }
#pragma unroll
    for (int u = 0; u < 4; ++u) {
      int row = r0 + 8 * w + 2 * u + half;
      *(float4*)(kc_out + (size_t)row * D_ + c) = kv[u];
      float p = qr.x * kv[u].x + qr.y * kv[u].y + qr.z * kv[u].z + qr.w * kv[u].w;
#pragma unroll
      for (int off = 16; off >= 1; off >>= 1) p += __shfl_xor(p, off, 64);
      if ((lane & 31) == 0) sc[row] = p;
    }
  }
  // tail row KV_: new K/V rows into caches + last score
  if (w == 0 && half == 0) {
    float4 kn = *(const float4*)(knp + c);
    float4 vn = *(const float4*)(vnp + c);
    *(float4*)(kc_out + (size_t)KV_ * D_ + c) = kn;
    *(float4*)(vc_out + (size_t)KV_ * D_ + c) = vn;
    float p = qr.x * kn.x + qr.y * kn.y + qr.z * kn.z + qr.w * kn.w;
#pragma unroll
    for (int off = 16; off >= 1; off >>= 1) p += __shfl_xor(p, off, 64);
    if (lane == 0) sc[KV_] = p;
  }
  __syncthreads();

  // ---- Softmax over sc[0..KV_] with mask ----
  float lm = -INFINITY;
  for (int k = tid; k < KV_ + 1; k += 256) {
    float s = sc[k];
    float mk = (k < KV_) ? mrow[k] : 1.f;
    s = (mk == 0.f) ? -INFINITY : s;
    sc[k] = s;
    lm = fmaxf(lm, s);
  }
#pragma unroll
  for (int off = 32; off >= 1; off >>= 1) lm = fmaxf(lm, __shfl_xor(lm, off, 64));
  if (lane == 0) red[w] = lm;
  __syncthreads();
  float M = fmaxf(fmaxf(red[0], red[1]), fmaxf(red[2], red[3]));
  float ls = 0.f;
  for (int k = tid; k < KV_ + 1; k += 256) {
    float e = __expf(sc[k] - M);
    sc[k] = e;
    ls += e;
  }
#pragma unroll
  for (int off = 32; off >= 1; off >>= 1) ls += __shfl_xor(ls, off, 64);
  __syncthreads();                 // everyone done reading red (M)
  if (lane == 0) red[w] = ls;
  __syncthreads();
  float invS = 1.f / (red[0] + red[1] + red[2] + red[3]);

  // ---- Pass 2: copy V rows + weighted accumulation ----
  float4 acc = {0.f, 0.f, 0.f, 0.f};
  for (int r0 = 0; r0 < KV_; r0 += 32) {
    float4 vv[4];
#pragma unroll
    for (int u = 0; u < 4; ++u) {
      int row = r0 + 8 * w + 2 * u + half;
      vv[u] = *(const float4*)(vc_in + (size_t)row * D_ + c);
    }
#pragma unroll
    for (int u = 0; u < 4; ++u) {
      int row = r0 + 8 * w + 2 * u + half;
      *(float4*)(vc_out + (size_t)row * D_ + c) = vv[u];
      float pw = sc[row];
      acc.x = fmaf(pw, vv[u].x, acc.x);
      acc.y = fmaf(pw, vv[u].y, acc.y);
      acc.z = fmaf(pw, vv[u].z, acc.z);
      acc.w = fmaf(pw, vv[u].w, acc.w);
    }
  }
  // combine halves of each wave (same column group)
  acc.x += __shfl_xor(acc.x, 32, 64);
  acc.y += __shfl_xor(acc.y, 32, 64);
  acc.z += __shfl_xor(acc.z, 32, 64);
  acc.w += __shfl_xor(acc.w, 32, 64);
  // tail row KV_ contribution (wave 0, lower half, post-combine)
  if (w == 0 && half == 0) {
    float4 vn = *(const float4*)(vnp + c);
    float pw = sc[KV_];
    acc.x = fmaf(pw, vn.x, acc.x);
    acc.y = fmaf(pw, vn.y, acc.y);
    acc.z = fmaf(pw, vn.z, acc.z);
    acc.w = fmaf(pw, vn.w, acc.w);
  }
  if (half == 0) *(float4*)(&ctx_s[w][c]) = acc;
  __syncthreads();
  if (tid < D_) {
    float v = (ctx_s[0][tid] + ctx_s[1][tid]) + (ctx_s[2][tid] + ctx_s[3][tid]);
    ctx[(size_t)b * E_ + h * D_ + tid] = v * invS;
  }
}

// ---------------------------------------------------------------------------
extern "C" void kernel_launch(void* const* d_in, const int* in_sizes, int n_in,
                              void* d_out, int out_size, void* d_ws, size_t ws_size,
                              hipStream_t stream) {
  const float* X      = (const float*)d_in[0];
  const float* kcache = (const float*)d_in[1];
  const float* vcache = (const float*)d_in[2];
  const float* mask   = (const float*)d_in[3];
  const float* Wqkv   = (const float*)d_in[4];
  const float* bqkv   = (const float*)d_in[5];
  const float* Wo     = (const float*)d_in[6];
  const float* bo     = (const float*)d_in[7];

  float* out      = (float*)d_out;                       // 32*2048
  float* Kc       = out + (size_t)B_ * E_;               // 32*16*2049*128
  float* Vc       = Kc + (size_t)B_ * H_ * (KV_ + 1) * D_;
  float* mask_new = Vc + (size_t)B_ * H_ * (KV_ + 1) * D_;

  float* qkv = (float*)d_ws;                 // 32*6144 fp32
  float* ctx = qkv + (size_t)B_ * NQKV;      // 32*2048 fp32

  gemm32<32><<<NQKV / 32, 256, 0, stream>>>(X, Wqkv, bqkv, qkv, E_, NQKV);
  attn_fused<<<B_ * H_, 256, 0, stream>>>(kcache, vcache, mask, qkv,
                                          Kc, Vc, ctx, mask_new);
  gemm32<16><<<E_ / 16, 256, 0, stream>>>(ctx, Wo, bo, out, E_, E_);
}